// Round 1
// baseline (803.336 us; speedup 1.0000x reference)
//
#include <hip/hip_runtime.h>

#define N_NODES 100000
#define N_EDGES 3200000

// W12 = W1 @ W2  (32x64 @ 64x128 -> 32x128)
__global__ void gemm_w12_kernel(const float* __restrict__ W1,
                                const float* __restrict__ W2,
                                float* __restrict__ W12) {
    int idx = blockIdx.x * blockDim.x + threadIdx.x;  // 4096 total
    if (idx >= 32 * 128) return;
    int r = idx >> 7;
    int c = idx & 127;
    float acc = 0.f;
#pragma unroll
    for (int k = 0; k < 64; ++k) acc += W1[r * 64 + k] * W2[k * 128 + c];
    W12[idx] = acc;
}

// out[row[e]][j] += val[e] * x[col[e]][j]   (32 features per node)
// one thread per (edge, feature); lanes 0..31 of each half-wave share an edge
__global__ void spmm32_kernel(const int* __restrict__ row,
                              const int* __restrict__ col,
                              const float* __restrict__ val,
                              const float* __restrict__ x,
                              float* __restrict__ out) {
    int id = blockIdx.x * blockDim.x + threadIdx.x;
    int e = id >> 5;
    int j = id & 31;
    if (e >= N_EDGES) return;
    int r = row[e];
    int c = col[e];
    float v = val[e];
    atomicAdd(&out[r * 32 + j], v * x[c * 32 + j]);
}

// out[i][j] = sum_k g2[i][k] * W12[k][j]   ([100000,32] @ [32,128])
__global__ void gemm_out_kernel(const float* __restrict__ g2,
                                const float* __restrict__ W12,
                                float* __restrict__ out) {
    __shared__ float w[32 * 128];
    for (int t = threadIdx.x; t < 32 * 128; t += blockDim.x) w[t] = W12[t];
    __syncthreads();
    int id = blockIdx.x * blockDim.x + threadIdx.x;  // exactly N_NODES*128
    int i = id >> 7;
    int j = id & 127;
    const float* g = g2 + i * 32;
    float acc = 0.f;
#pragma unroll
    for (int k = 0; k < 32; ++k) acc += g[k] * w[k * 128 + j];
    out[id] = acc;
}

extern "C" void kernel_launch(void* const* d_in, const int* in_sizes, int n_in,
                              void* d_out, int out_size, void* d_ws, size_t ws_size,
                              hipStream_t stream) {
    const float* feat = (const float*)d_in[0];   // [N, 32]
    const float* W1   = (const float*)d_in[1];   // [32, 64]
    const float* W2   = (const float*)d_in[2];   // [64, 128]
    const int*   erow = (const int*)d_in[3];     // [E]
    const int*   ecol = (const int*)d_in[4];     // [E]
    const float* eval_= (const float*)d_in[5];   // [E]
    float* out = (float*)d_out;                  // [N, 128]

    // workspace layout: W12 [32*128] | g1 [N*32] | g2 [N*32]
    float* W12 = (float*)d_ws;
    float* g1  = W12 + 32 * 128;
    float* g2  = g1 + (size_t)N_NODES * 32;

    // zero both spmm accumulators (contiguous)
    hipMemsetAsync(g1, 0, (size_t)N_NODES * 32 * 2 * sizeof(float), stream);

    gemm_w12_kernel<<<16, 256, 0, stream>>>(W1, W2, W12);

    // g1 = A @ feat
    spmm32_kernel<<<(N_EDGES * 32) / 256, 256, 0, stream>>>(erow, ecol, eval_, feat, g1);
    // g2 = A @ g1
    spmm32_kernel<<<(N_EDGES * 32) / 256, 256, 0, stream>>>(erow, ecol, eval_, g1, g2);

    // out = g2 @ W12
    gemm_out_kernel<<<(N_NODES * 128) / 256, 256, 0, stream>>>(g2, W12, out);
}